// Round 3
// baseline (435.447 us; speedup 1.0000x reference)
//
#include <hip/hip_runtime.h>
#include <cstdint>
#include <cstddef>

#define HWDIM 56
#define NBATCH 8
#define NHEADS 16
#define HDIM 32
#define CDIM 512
#define QKV_N 1536
#define KSZ 7
#define RAD 3
#define NPIX (NBATCH*HWDIM*HWDIM)          // 25088
#define SCALE 0.17677669529663687f         // 32^-0.5

typedef unsigned short u16;
typedef __bf16 bf16x8 __attribute__((ext_vector_type(8)));
typedef float  f32x4  __attribute__((ext_vector_type(4)));

// ---- bf16 helpers (RNE) ----
__device__ __forceinline__ u16 f2bf(float x) {
    union { float f; unsigned u; } v; v.f = x;
    unsigned r = v.u + 0x7fff + ((v.u >> 16) & 1);
    return (u16)(r >> 16);
}
__device__ __forceinline__ float bf2f(u16 h) {
    union { float f; unsigned u; } v; v.u = ((unsigned)h) << 16; return v.f;
}

// async global->LDS, 16B per lane. Per-lane lds ptr is linear in lane
// (base + lane*16) which matches the HW wave-uniform-base+lane*size rule
// (m104/m108); swizzling is done on the GLOBAL source address (m173).
__device__ __forceinline__ void gload16(const void* g, void* l) {
    __builtin_amdgcn_global_load_lds(
        (const __attribute__((address_space(1))) unsigned int*)g,
        (__attribute__((address_space(3))) unsigned int*)l, 16, 0, 0);
}

// ---------------------------------------------------------------------------
// prep: fp32 -> (hi, lo) bf16 split, elementwise (vectorized x4)
// ---------------------------------------------------------------------------
__global__ __launch_bounds__(256)
void split_f32(const float* __restrict__ in, u16* __restrict__ hi,
               u16* __restrict__ lo, int n4)
{
    int i = blockIdx.x * 256 + threadIdx.x;
    if (i >= n4) return;
    float4 v = ((const float4*)in)[i];
    ushort4 h, l;
    h.x = f2bf(v.x); l.x = f2bf(v.x - bf2f(h.x));
    h.y = f2bf(v.y); l.y = f2bf(v.y - bf2f(h.y));
    h.z = f2bf(v.z); l.z = f2bf(v.z - bf2f(h.z));
    h.w = f2bf(v.w); l.w = f2bf(v.w - bf2f(h.w));
    ((ushort4*)hi)[i] = h;
    ((ushort4*)lo)[i] = l;
}

// ---------------------------------------------------------------------------
// prep: W[K][N] fp32 -> Wt[N][K] (hi, lo) bf16   (weights only, small;
// uncoalesced reads are L2-resident after first touch: W total < 4 MB)
// ---------------------------------------------------------------------------
__global__ __launch_bounds__(256)
void transpose_split(const float* __restrict__ w, u16* __restrict__ th,
                     u16* __restrict__ tl, int K, int N)
{
    int idx = blockIdx.x * 256 + threadIdx.x;
    if (idx >= K * N) return;
    int n = idx / K, k = idx - n * K;
    float v = w[(size_t)k * N + n];
    u16 h = f2bf(v);
    th[idx] = h;
    tl[idx] = f2bf(v - bf2f(h));
}

// ---------------------------------------------------------------------------
// split-bf16 MFMA GEMM + bias:  C[M,N] fp32 = A @ B^T (hi+lo decomposed)
// A{h,l}: [M][K] bf16 row-major; B{h,l}: [N][K] bf16 (pre-transposed).
// 128x128 tile, BK=32, 4 waves (2x2, 64x64 each), 16x16x32 MFMA, 3 per
// fragment pair: lo*hi + hi*lo + hi*hi (dropped lo*lo ~ 2^-18 rel).
// Staging: global_load_lds w=16, LINEAR LDS dest; XOR swizzle
// kb ^= (row>>1)&3 applied on the global SOURCE and on the ds_read side
// (both-sides rule #21) -> ds_read_b128 lands 2-way (free, m136).
// Requires M%128==0, N%128==0, K%32==0 (25088/1536/512 all satisfy).
// ---------------------------------------------------------------------------
__global__ __launch_bounds__(256, 2)
void gemm_split_bf16(const u16* __restrict__ Ah, const u16* __restrict__ Al,
                     const u16* __restrict__ Bh, const u16* __restrict__ Bl,
                     const float* __restrict__ bias, float* __restrict__ C,
                     int M, int N, int K)
{
    __shared__ __bf16 sAh[128 * 32], sAl[128 * 32];
    __shared__ __bf16 sBh[128 * 32], sBl[128 * 32];

    const int nbx  = N >> 7;
    const int bx   = blockIdx.x % nbx;
    const int by   = blockIdx.x / nbx;
    const int m0   = by << 7;
    const int n0   = bx << 7;
    const int tid  = threadIdx.x;
    const int lane = tid & 63;
    const int wid  = tid >> 6;
    const int wr   = wid >> 1;      // wave row (0..1) -> 64 rows
    const int wc   = wid & 1;       // wave col (0..1) -> 64 cols

    f32x4 acc[4][4];
#pragma unroll
    for (int m = 0; m < 4; ++m)
#pragma unroll
        for (int n = 0; n < 4; ++n)
#pragma unroll
            for (int j = 0; j < 4; ++j) acc[m][n][j] = 0.f;

    // fragment read offsets (elems), swizzled to match staging
    int a_off[4], b_off[4];
#pragma unroll
    for (int m = 0; m < 4; ++m) {
        int row = wr * 64 + m * 16 + (lane & 15);
        int kb  = lane >> 4;
        a_off[m] = row * 32 + (kb ^ ((row >> 1) & 3)) * 8;
    }
#pragma unroll
    for (int n = 0; n < 4; ++n) {
        int row = wc * 64 + n * 16 + (lane & 15);
        int kb  = lane >> 4;
        b_off[n] = row * 32 + (kb ^ ((row >> 1) & 3)) * 8;
    }

    // staging: 16B chunk s = it*256+tid -> LDS slot s (linear); slot
    // (row, kbs) receives global K-chunk kbg = kbs ^ ((row>>1)&3)
    int s_row[2], s_kbg[2], s_lds[2];
#pragma unroll
    for (int it = 0; it < 2; ++it) {
        int s = it * 256 + tid;
        int row = s >> 2, kbs = s & 3;
        s_row[it] = row;
        s_kbg[it] = kbs ^ ((row >> 1) & 3);
        s_lds[it] = s * 8;
    }

    for (int kt = 0; kt < K; kt += 32) {
#pragma unroll
        for (int it = 0; it < 2; ++it) {
            const size_t ga = (size_t)(m0 + s_row[it]) * K + kt + s_kbg[it] * 8;
            const size_t gb = (size_t)(n0 + s_row[it]) * K + kt + s_kbg[it] * 8;
            gload16(Ah + ga, (void*)(sAh + s_lds[it]));
            gload16(Al + ga, (void*)(sAl + s_lds[it]));
            gload16(Bh + gb, (void*)(sBh + s_lds[it]));
            gload16(Bl + gb, (void*)(sBl + s_lds[it]));
        }
        __syncthreads();   // compiler drains vmcnt(0) before s_barrier

        bf16x8 ah[4], al[4], bh[4], bl[4];
#pragma unroll
        for (int m = 0; m < 4; ++m) {
            ah[m] = *(const bf16x8*)(sAh + a_off[m]);
            al[m] = *(const bf16x8*)(sAl + a_off[m]);
        }
#pragma unroll
        for (int n = 0; n < 4; ++n) {
            bh[n] = *(const bf16x8*)(sBh + b_off[n]);
            bl[n] = *(const bf16x8*)(sBl + b_off[n]);
        }
#pragma unroll
        for (int m = 0; m < 4; ++m)
#pragma unroll
            for (int n = 0; n < 4; ++n) {
                acc[m][n] = __builtin_amdgcn_mfma_f32_16x16x32_bf16(al[m], bh[n], acc[m][n], 0, 0, 0);
                acc[m][n] = __builtin_amdgcn_mfma_f32_16x16x32_bf16(ah[m], bl[n], acc[m][n], 0, 0, 0);
                acc[m][n] = __builtin_amdgcn_mfma_f32_16x16x32_bf16(ah[m], bh[n], acc[m][n], 0, 0, 0);
            }
        __syncthreads();
    }

    // epilogue: C/D layout col=lane&15, row=(lane>>4)*4+j  [m89-verified]
#pragma unroll
    for (int m = 0; m < 4; ++m) {
        const int rbase = m0 + wr * 64 + m * 16 + (lane >> 4) * 4;
#pragma unroll
        for (int n = 0; n < 4; ++n) {
            const int col = n0 + wc * 64 + n * 16 + (lane & 15);
            const float bv = bias[col];
#pragma unroll
            for (int j = 0; j < 4; ++j)
                C[(size_t)(rbase + j) * N + col] = acc[m][n][j] + bv;
        }
    }
}

// ---------------------------------------------------------------------------
// NATTEN 7x7 neighborhood attention (fp32 in, hi/lo bf16 out).
// Grid: (16 tiles [4x4 of 16x16 pixels], head, batch). Block: 256 threads,
// one pixel each. K halo (22x22x32 fp32, XOR-swizzled float4 slots) staged
// in LDS; 49 logits in registers; same LDS buffer then reused for V.
// ---------------------------------------------------------------------------
__global__ __launch_bounds__(256)
void natten2d(const float* __restrict__ qkv, const float* __restrict__ rpb,
              u16* __restrict__ oh, u16* __restrict__ ol)
{
    __shared__ float tile[484 * 32];   // 61,952 B; [pix][slot^(pix&7)]

    const int tix  = blockIdx.x & 3;
    const int tiy  = blockIdx.x >> 2;
    const int head = blockIdx.y;
    const int b    = blockIdx.z;
    const int r0   = tiy * 16;
    const int c0   = tix * 16;
    const int bh0  = min(max(r0 - RAD, 0), HWDIM - 22);   // halo origin
    const int cw0  = min(max(c0 - RAD, 0), HWDIM - 22);

    const int tid = threadIdx.x;
    const int ph  = tid >> 4;
    const int pw  = tid & 15;
    const int h   = r0 + ph;
    const int w   = c0 + pw;
    const bool active = (h < HWDIM) && (w < HWDIM);
    const int hc = min(h, HWDIM - 1);
    const int wc = min(w, HWDIM - 1);
    const size_t pixg = (size_t)(b * HWDIM + hc) * HWDIM + wc;

    // ---- load q (scaled) ----
    float q[32];
    {
        const float* qp = qkv + pixg * QKV_N + head * HDIM;
#pragma unroll
        for (int d4 = 0; d4 < 8; ++d4) {
            float4 v = *(const float4*)(qp + d4 * 4);
            q[d4 * 4 + 0] = v.x * SCALE;
            q[d4 * 4 + 1] = v.y * SCALE;
            q[d4 * 4 + 2] = v.z * SCALE;
            q[d4 * 4 + 3] = v.w * SCALE;
        }
    }

    const int sh      = min(max(h - RAD, 0), HWDIM - KSZ);  // window start
    const int sw      = min(max(w - RAD, 0), HWDIM - KSZ);
    const int lh0     = sh - bh0;                            // 0..15
    const int lw0     = sw - cw0;
    const int bh_base = sh + (KSZ - 1) - h;                  // rpb row base
    const int bw_base = sw + (KSZ - 1) - w;

    // ---- stage K into LDS ----
    for (int i = tid; i < 484 * 8; i += 256) {
        const int pix = i >> 3;
        const int d4  = i & 7;
        const int row = pix / 22;
        const int col = pix - row * 22;
        const float4 kv = *(const float4*)(qkv +
            ((size_t)((b * HWDIM + bh0 + row) * HWDIM + cw0 + col)) * QKV_N
            + CDIM + head * HDIM + d4 * 4);
        *(float4*)&tile[pix * 32 + (((d4 ^ pix) & 7) << 2)] = kv;
    }
    __syncthreads();

    // ---- QK^T: 49 logits per pixel ----
    float logit[49];
    float mmax = -1e30f;
    if (active) {
#pragma unroll
        for (int a = 0; a < KSZ; ++a) {
#pragma unroll
            for (int bb = 0; bb < KSZ; ++bb) {
                const int pix = (lh0 + a) * 22 + (lw0 + bb);
                const int swz = pix & 7;
                float s = 0.f;
#pragma unroll
                for (int d4 = 0; d4 < 8; ++d4) {
                    const float4 kv = *(const float4*)&tile[pix * 32 + (((d4 ^ swz) & 7) << 2)];
                    s = fmaf(q[d4 * 4 + 0], kv.x, s);
                    s = fmaf(q[d4 * 4 + 1], kv.y, s);
                    s = fmaf(q[d4 * 4 + 2], kv.z, s);
                    s = fmaf(q[d4 * 4 + 3], kv.w, s);
                }
                s += rpb[head * 169 + (bh_base + a) * 13 + (bw_base + bb)];
                logit[a * KSZ + bb] = s;
                mmax = fmaxf(mmax, s);
            }
        }
    }
    __syncthreads();   // all K reads complete before V overwrites the buffer

    // ---- stage V into LDS (same buffer) ----
    for (int i = tid; i < 484 * 8; i += 256) {
        const int pix = i >> 3;
        const int d4  = i & 7;
        const int row = pix / 22;
        const int col = pix - row * 22;
        const float4 vv = *(const float4*)(qkv +
            ((size_t)((b * HWDIM + bh0 + row) * HWDIM + cw0 + col)) * QKV_N
            + 2 * CDIM + head * HDIM + d4 * 4);
        *(float4*)&tile[pix * 32 + (((d4 ^ pix) & 7) << 2)] = vv;
    }
    __syncthreads();

    // ---- softmax + PV ----
    if (active) {
        float accv[32];
#pragma unroll
        for (int d = 0; d < 32; ++d) accv[d] = 0.f;
        float lsum = 0.f;
#pragma unroll
        for (int a = 0; a < KSZ; ++a) {
#pragma unroll
            for (int bb = 0; bb < KSZ; ++bb) {
                const float p = __expf(logit[a * KSZ + bb] - mmax);
                lsum += p;
                const int pix = (lh0 + a) * 22 + (lw0 + bb);
                const int swz = pix & 7;
#pragma unroll
                for (int d4 = 0; d4 < 8; ++d4) {
                    const float4 vv = *(const float4*)&tile[pix * 32 + (((d4 ^ swz) & 7) << 2)];
                    accv[d4 * 4 + 0] = fmaf(p, vv.x, accv[d4 * 4 + 0]);
                    accv[d4 * 4 + 1] = fmaf(p, vv.y, accv[d4 * 4 + 1]);
                    accv[d4 * 4 + 2] = fmaf(p, vv.z, accv[d4 * 4 + 2]);
                    accv[d4 * 4 + 3] = fmaf(p, vv.w, accv[d4 * 4 + 3]);
                }
            }
        }
        const float inv = 1.f / lsum;
        u16* oph = oh + pixg * CDIM + head * HDIM;
        u16* opl = ol + pixg * CDIM + head * HDIM;
#pragma unroll
        for (int d4 = 0; d4 < 8; ++d4) {
            float4 o;
            o.x = accv[d4 * 4 + 0] * inv;
            o.y = accv[d4 * 4 + 1] * inv;
            o.z = accv[d4 * 4 + 2] * inv;
            o.w = accv[d4 * 4 + 3] * inv;
            ushort4 h4, l4;
            h4.x = f2bf(o.x); l4.x = f2bf(o.x - bf2f(h4.x));
            h4.y = f2bf(o.y); l4.y = f2bf(o.y - bf2f(h4.y));
            h4.z = f2bf(o.z); l4.z = f2bf(o.z - bf2f(h4.z));
            h4.w = f2bf(o.w); l4.w = f2bf(o.w - bf2f(h4.w));
            *(ushort4*)(oph + d4 * 4) = h4;
            *(ushort4*)(opl + d4 * 4) = l4;
        }
    }
}

// ---------------------------------------------------------------------------
extern "C" void kernel_launch(void* const* d_in, const int* in_sizes, int n_in,
                              void* d_out, int out_size, void* d_ws, size_t ws_size,
                              hipStream_t stream)
{
    const float* x      = (const float*)d_in[0];
    const float* w_qkv  = (const float*)d_in[1];
    const float* b_qkv  = (const float*)d_in[2];
    const float* rpb    = (const float*)d_in[3];
    const float* w_proj = (const float*)d_in[4];
    const float* b_proj = (const float*)d_in[5];
    float* outp = (float*)d_out;

    // workspace carve-up (~210 MB); all offsets 16B-aligned.
    char* p = (char*)d_ws;
    float* qkv = (float*)p;  p += (size_t)NPIX * QKV_N * 4;    // 154.1 MB
    u16* xh = (u16*)p;       p += (size_t)NPIX * CDIM * 2;     // 25.7 MB
    u16* xl = (u16*)p;       p += (size_t)NPIX * CDIM * 2;     // 25.7 MB
    u16* wqh = (u16*)p;      p += (size_t)QKV_N * CDIM * 2;    // 1.6 MB
    u16* wql = (u16*)p;      p += (size_t)QKV_N * CDIM * 2;
    u16* wph = (u16*)p;      p += (size_t)CDIM * CDIM * 2;     // 0.5 MB
    u16* wpl = (u16*)p;      p += (size_t)CDIM * CDIM * 2;
    u16* ath = xh;           // alias: x splits dead after gemm1
    u16* atl = xl;

    // 1) splits / weight transposes
    {
        const int n4 = NPIX * CDIM / 4;
        split_f32<<<(n4 + 255) / 256, 256, 0, stream>>>(x, xh, xl, n4);
        transpose_split<<<(CDIM * QKV_N + 255) / 256, 256, 0, stream>>>(
            w_qkv, wqh, wql, CDIM, QKV_N);
        transpose_split<<<(CDIM * CDIM + 255) / 256, 256, 0, stream>>>(
            w_proj, wph, wpl, CDIM, CDIM);
    }
    // 2) qkv = x @ w_qkv + b_qkv   (fp32 out)
    gemm_split_bf16<<<(NPIX / 128) * (QKV_N / 128), 256, 0, stream>>>(
        xh, xl, wqh, wql, b_qkv, qkv, NPIX, QKV_N, CDIM);
    // 3) neighborhood attention -> hi/lo bf16
    natten2d<<<dim3(16, NHEADS, NBATCH), 256, 0, stream>>>(qkv, rpb, ath, atl);
    // 4) out = attn @ w_proj + b_proj
    gemm_split_bf16<<<(NPIX / 128) * (CDIM / 128), 256, 0, stream>>>(
        ath, atl, wph, wpl, b_proj, outp, NPIX, CDIM, CDIM);
}